// Round 3
// baseline (1605.444 us; speedup 1.0000x reference)
//
#include <hip/hip_runtime.h>
#include <math.h>

#define D 128

// WT[k][c] = W_enc[c][k]  (so encoder LDS reads are contiguous in c)
__global__ void transpose_w_kernel(const float* __restrict__ W, float* __restrict__ WT) {
    int t = blockIdx.x * blockDim.x + threadIdx.x;
    if (t < D * D) {
        int c = t >> 7, k = t & (D - 1);
        WT[k * D + c] = W[c * D + k];
    }
}

// x[n][c] = b[c] + sum_k nf[n][k] * W_enc[c][k]
// 32-row tile, 256 threads: thread owns 4 rows x 4 consecutive cols.
// LDS: WT 64KB + NF 16KB = 80KB -> 2 blocks/CU.
__global__ __launch_bounds__(256) void encoder_kernel(
    const float* __restrict__ nf, const float* __restrict__ WTg,
    const float* __restrict__ b, float* __restrict__ x, int nN) {
    __shared__ float WT[D * D];
    __shared__ float NF[32 * D];
    const int t = threadIdx.x;
    const int row0 = blockIdx.x * 32;

    for (int i = t; i < (D * D) / 4; i += 256)
        ((float4*)WT)[i] = ((const float4*)WTg)[i];
    for (int i = t; i < (32 * D) / 4; i += 256) {
        int r = i >> 5;
        int gr = row0 + r;
        float4 v = make_float4(0.f, 0.f, 0.f, 0.f);
        if (gr < nN) v = ((const float4*)(nf + (size_t)gr * D))[i & 31];
        ((float4*)NF)[i] = v;
    }
    __syncthreads();

    const int c4 = (t & 31) * 4;   // 4 consecutive output cols
    const int rg = t >> 5;         // 8 row-groups of 4 rows
    float4 bv = *(const float4*)(b + c4);
    float acc[4][4];
#pragma unroll
    for (int r = 0; r < 4; ++r) {
        acc[r][0] = bv.x; acc[r][1] = bv.y; acc[r][2] = bv.z; acc[r][3] = bv.w;
    }
#pragma unroll 4
    for (int k = 0; k < D; k += 4) {
        float4 w0 = *(const float4*)(WT + (k + 0) * D + c4);
        float4 w1 = *(const float4*)(WT + (k + 1) * D + c4);
        float4 w2 = *(const float4*)(WT + (k + 2) * D + c4);
        float4 w3 = *(const float4*)(WT + (k + 3) * D + c4);
#pragma unroll
        for (int r = 0; r < 4; ++r) {
            float4 nv = *(const float4*)(NF + (rg * 4 + r) * D + k);
            acc[r][0] += nv.x * w0.x + nv.y * w1.x + nv.z * w2.x + nv.w * w3.x;
            acc[r][1] += nv.x * w0.y + nv.y * w1.y + nv.z * w2.y + nv.w * w3.y;
            acc[r][2] += nv.x * w0.z + nv.y * w1.z + nv.z * w2.z + nv.w * w3.z;
            acc[r][3] += nv.x * w0.w + nv.y * w1.w + nv.z * w2.w + nv.w * w3.w;
        }
    }
#pragma unroll
    for (int r = 0; r < 4; ++r) {
        int gr = row0 + rg * 4 + r;
        if (gr < nN)
            *(float4*)(x + (size_t)gr * D + c4) =
                make_float4(acc[r][0], acc[r][1], acc[r][2], acc[r][3]);
    }
}

// One wave processes 64 edges per chunk: indices loaded coalesced once.
// Degree: one fully-parallel atomic per lane (own edge).
// Feature scatter: per-edge broadcast via readlane (wave-uniform base
// addresses -> SGPR); each lane owns 2 of 128 features: 1 float2 gather
// + 2 hardware f32 atomics per edge.
__global__ __launch_bounds__(256) void scatter_kernel(
    const float* __restrict__ x, const int* __restrict__ esrc,
    const int* __restrict__ edst, float* __restrict__ agg,
    float* __restrict__ deg, int nE) {
    const int lane = threadIdx.x & 63;
    const int wave = (blockIdx.x * blockDim.x + threadIdx.x) >> 6;
    const int nw = (gridDim.x * blockDim.x) >> 6;
    const size_t feat = (size_t)(lane * 2);
    const float* xf = x + feat;
    float* af = agg + feat;
    for (int base = wave * 64; base < nE; base += nw * 64) {
        int e = base + lane;
        int s = 0, d = 0;
        if (e < nE) {
            s = esrc[e];
            d = edst[e];
            unsafeAtomicAdd(deg + d, 1.0f);   // parallel, 1 per edge
        }
        int cnt = nE - base; if (cnt > 64) cnt = 64;
#pragma unroll 4
        for (int i = 0; i < cnt; ++i) {
            int si = __builtin_amdgcn_readlane(s, i);
            int di = __builtin_amdgcn_readlane(d, i);
            float2 v = *(const float2*)(xf + (size_t)si * D);
            float* ap = af + (size_t)di * D;
            unsafeAtomicAdd(ap, v.x);
            unsafeAtomicAdd(ap + 1, v.y);
        }
    }
}

// out = x2 * sigmoid(x2 . Wa + ba),  x2 = x + where(deg>0, agg/max(deg,1), x)
// One wave per node; lane owns 2 features; wave shuffle-reduce for the dot.
__global__ __launch_bounds__(256) void finalize_kernel(
    const float* x, const float* __restrict__ agg, const float* __restrict__ deg,
    const float* __restrict__ Wa, const float* __restrict__ ba,
    float* out, int nN) {
    const int lane = threadIdx.x & 63;
    const int wave = (blockIdx.x * blockDim.x + threadIdx.x) >> 6;
    const int nw = (gridDim.x * blockDim.x) >> 6;
    float2 wv = ((const float2*)Wa)[lane];
    float bias = ba[0];
    for (int n = wave; n < nN; n += nw) {
        float2 xv = ((const float2*)(x + (size_t)n * D))[lane];
        float2 av = ((const float2*)(agg + (size_t)n * D))[lane];
        float dg = deg[n];
        float inv = 1.0f / fmaxf(dg, 1.0f);
        float nx0 = (dg > 0.0f) ? av.x * inv : xv.x;
        float nx1 = (dg > 0.0f) ? av.y * inv : xv.y;
        float x20 = xv.x + nx0, x21 = xv.y + nx1;
        float p = x20 * wv.x + x21 * wv.y;
#pragma unroll
        for (int off = 32; off > 0; off >>= 1) p += __shfl_xor(p, off);
        float a = 1.0f / (1.0f + expf(-(p + bias)));
        *(float2*)(out + (size_t)n * D + lane * 2) = make_float2(x20 * a, x21 * a);
    }
}

extern "C" void kernel_launch(void* const* d_in, const int* in_sizes, int n_in,
                              void* d_out, int out_size, void* d_ws, size_t ws_size,
                              hipStream_t stream) {
    const float* nf     = (const float*)d_in[0];
    const int*   esrc   = (const int*)d_in[1];
    const int*   edst   = (const int*)d_in[2];
    const float* W_enc  = (const float*)d_in[3];
    const float* b_enc  = (const float*)d_in[4];
    const float* W_attn = (const float*)d_in[5];
    const float* b_attn = (const float*)d_in[6];
    float* out = (float*)d_out;
    const int nN = in_sizes[0] / D;
    const int nE = in_sizes[1];

    // ws layout: agg [nN*D] | deg [nN] | WT [D*D]   (~51.7 MB)
    float* agg = (float*)d_ws;
    float* deg = agg + (size_t)nN * D;
    float* WT  = deg + nN;

    hipMemsetAsync(d_ws, 0, ((size_t)nN * D + nN) * sizeof(float), stream);
    transpose_w_kernel<<<(D * D + 255) / 256, 256, 0, stream>>>(W_enc, WT);
    // x is staged in d_out (it has exactly nN*D floats), finalized in place.
    encoder_kernel<<<(nN + 31) / 32, 256, 0, stream>>>(nf, WT, b_enc, out, nN);
    scatter_kernel<<<2048, 256, 0, stream>>>(out, esrc, edst, agg, deg, nE);
    finalize_kernel<<<2048, 256, 0, stream>>>(out, agg, deg, W_attn, b_attn, out, nN);
}

// Round 8
// 447.580 us; speedup vs baseline: 3.5869x; 3.5869x over previous
//
#include <hip/hip_runtime.h>
#include <math.h>

#define D 128

// ---------------- shared: W transpose ----------------
// WT[k][c] = W_enc[c][k]  (so encoder LDS reads are contiguous in c)
__global__ void transpose_w_kernel(const float* __restrict__ W, float* __restrict__ WT) {
    int t = blockIdx.x * blockDim.x + threadIdx.x;
    if (t < D * D) {
        int c = t >> 7, k = t & (D - 1);
        WT[k * D + c] = W[c * D + k];
    }
}

// ---------------- encoder ----------------
// x[n][c] = b[c] + sum_k nf[n][k] * W_enc[c][k]
// 32-row tile, 256 threads: thread owns 4 rows x 4 consecutive cols.
__global__ __launch_bounds__(256) void encoder_kernel(
    const float* __restrict__ nf, const float* __restrict__ WTg,
    const float* __restrict__ b, float* __restrict__ x, int nN) {
    __shared__ float WT[D * D];
    __shared__ float NF[32 * D];
    const int t = threadIdx.x;
    const int row0 = blockIdx.x * 32;

    for (int i = t; i < (D * D) / 4; i += 256)
        ((float4*)WT)[i] = ((const float4*)WTg)[i];
    for (int i = t; i < (32 * D) / 4; i += 256) {
        int r = i >> 5;
        int gr = row0 + r;
        float4 v = make_float4(0.f, 0.f, 0.f, 0.f);
        if (gr < nN) v = ((const float4*)(nf + (size_t)gr * D))[i & 31];
        ((float4*)NF)[i] = v;
    }
    __syncthreads();

    const int c4 = (t & 31) * 4;
    const int rg = t >> 5;
    float4 bv = *(const float4*)(b + c4);
    float acc[4][4];
#pragma unroll
    for (int r = 0; r < 4; ++r) {
        acc[r][0] = bv.x; acc[r][1] = bv.y; acc[r][2] = bv.z; acc[r][3] = bv.w;
    }
#pragma unroll 4
    for (int k = 0; k < D; k += 4) {
        float4 w0 = *(const float4*)(WT + (k + 0) * D + c4);
        float4 w1 = *(const float4*)(WT + (k + 1) * D + c4);
        float4 w2 = *(const float4*)(WT + (k + 2) * D + c4);
        float4 w3 = *(const float4*)(WT + (k + 3) * D + c4);
#pragma unroll
        for (int r = 0; r < 4; ++r) {
            float4 nv = *(const float4*)(NF + (rg * 4 + r) * D + k);
            acc[r][0] += nv.x * w0.x + nv.y * w1.x + nv.z * w2.x + nv.w * w3.x;
            acc[r][1] += nv.x * w0.y + nv.y * w1.y + nv.z * w2.y + nv.w * w3.y;
            acc[r][2] += nv.x * w0.z + nv.y * w1.z + nv.z * w2.z + nv.w * w3.z;
            acc[r][3] += nv.x * w0.w + nv.y * w1.w + nv.z * w2.w + nv.w * w3.w;
        }
    }
#pragma unroll
    for (int r = 0; r < 4; ++r) {
        int gr = row0 + rg * 4 + r;
        if (gr < nN)
            *(float4*)(x + (size_t)gr * D + c4) =
                make_float4(acc[r][0], acc[r][1], acc[r][2], acc[r][3]);
    }
}

// ---------------- CSR build: histogram / offsets / fill ----------------
__global__ void hist_kernel(const int* __restrict__ edst, int* __restrict__ deg, int nE) {
    int e = blockIdx.x * blockDim.x + threadIdx.x;
    if (e < nE) atomicAdd(&deg[edst[e]], 1);
}

// offs[i] = running base for node i's slot range. Range ASSIGNMENT order is
// arbitrary (one atomic per 256-node block) — only disjointness matters.
__global__ __launch_bounds__(256) void offs_kernel(
    const int* __restrict__ deg, int* __restrict__ offs,
    int* __restrict__ gcur, int nN) {
    __shared__ int wsum[4];
    __shared__ int sbase;
    const int t = threadIdx.x, lane = t & 63, w = t >> 6;
    const int i = blockIdx.x * 256 + t;
    int d = (i < nN) ? deg[i] : 0;
    int sc = d;                       // inclusive scan within wave
#pragma unroll
    for (int o = 1; o < 64; o <<= 1) {
        int v = __shfl_up(sc, o);
        if (lane >= o) sc += v;
    }
    if (lane == 63) wsum[w] = sc;
    __syncthreads();
    if (t == 0) {
        int s0 = wsum[0], s1 = wsum[1], s2 = wsum[2], s3 = wsum[3];
        sbase = atomicAdd(gcur, s0 + s1 + s2 + s3);
        wsum[0] = 0; wsum[1] = s0; wsum[2] = s0 + s1; wsum[3] = s0 + s1 + s2;
    }
    __syncthreads();
    if (i < nN) offs[i] = sbase + wsum[w] + (sc - d);
}

__global__ void fill_kernel(const int* __restrict__ esrc, const int* __restrict__ edst,
                            const int* __restrict__ offs, int* __restrict__ cur,
                            int* __restrict__ slots, int nE) {
    int e = blockIdx.x * blockDim.x + threadIdx.x;
    if (e < nE) {
        int d = edst[e];
        int pos = atomicAdd(&cur[d], 1);
        slots[offs[d] + pos] = esrc[e];
    }
}

// ---------------- fused gather + finalize ----------------
// One wave per dst node; lane owns 2 features. Neighbor loop: slot ids loaded
// coalesced (64/chunk), broadcast via readlane; 8 independent accumulators
// keep 8 gathers in flight (deg avg 16 -> 2 latency rounds). Then
// mean/residual/attention-gate in-wave, single coalesced write.
__global__ __launch_bounds__(256) void gather_finalize_kernel(
    const float* __restrict__ x, const int* __restrict__ slots,
    const int* __restrict__ offs, const int* __restrict__ deg,
    const float* __restrict__ Wa, const float* __restrict__ ba,
    float* __restrict__ out, int nN) {
    const int lane = threadIdx.x & 63;
    const int node = (blockIdx.x * blockDim.x + threadIdx.x) >> 6;
    if (node >= nN) return;
    const int dg = deg[node];
    const int off = offs[node];
    const float* xf = x + lane * 2;

    float2 a0 = make_float2(0.f, 0.f), a1 = a0, a2 = a0, a3 = a0;
    float2 a4 = a0, a5 = a0, a6 = a0, a7 = a0;
    for (int base = 0; base < dg; base += 64) {
        int cnt = dg - base; if (cnt > 64) cnt = 64;
        int sl = (base + lane < dg) ? slots[off + base + lane] : 0;
        int i = 0;
        for (; i + 8 <= cnt; i += 8) {
            int s0 = __builtin_amdgcn_readlane(sl, i);
            int s1 = __builtin_amdgcn_readlane(sl, i + 1);
            int s2 = __builtin_amdgcn_readlane(sl, i + 2);
            int s3 = __builtin_amdgcn_readlane(sl, i + 3);
            int s4 = __builtin_amdgcn_readlane(sl, i + 4);
            int s5 = __builtin_amdgcn_readlane(sl, i + 5);
            int s6 = __builtin_amdgcn_readlane(sl, i + 6);
            int s7 = __builtin_amdgcn_readlane(sl, i + 7);
            float2 v0 = *(const float2*)(xf + (size_t)s0 * D);
            float2 v1 = *(const float2*)(xf + (size_t)s1 * D);
            float2 v2 = *(const float2*)(xf + (size_t)s2 * D);
            float2 v3 = *(const float2*)(xf + (size_t)s3 * D);
            float2 v4 = *(const float2*)(xf + (size_t)s4 * D);
            float2 v5 = *(const float2*)(xf + (size_t)s5 * D);
            float2 v6 = *(const float2*)(xf + (size_t)s6 * D);
            float2 v7 = *(const float2*)(xf + (size_t)s7 * D);
            a0.x += v0.x; a0.y += v0.y;
            a1.x += v1.x; a1.y += v1.y;
            a2.x += v2.x; a2.y += v2.y;
            a3.x += v3.x; a3.y += v3.y;
            a4.x += v4.x; a4.y += v4.y;
            a5.x += v5.x; a5.y += v5.y;
            a6.x += v6.x; a6.y += v6.y;
            a7.x += v7.x; a7.y += v7.y;
        }
        for (; i < cnt; ++i) {
            int s0 = __builtin_amdgcn_readlane(sl, i);
            float2 v0 = *(const float2*)(xf + (size_t)s0 * D);
            a0.x += v0.x; a0.y += v0.y;
        }
    }
    float sx = ((a0.x + a1.x) + (a2.x + a3.x)) + ((a4.x + a5.x) + (a6.x + a7.x));
    float sy = ((a0.y + a1.y) + (a2.y + a3.y)) + ((a4.y + a5.y) + (a6.y + a7.y));

    float2 xv = *(const float2*)(x + (size_t)node * D + lane * 2);
    float inv = (dg > 0) ? 1.0f / (float)dg : 0.f;
    float nx0 = (dg > 0) ? sx * inv : xv.x;
    float nx1 = (dg > 0) ? sy * inv : xv.y;
    float x20 = xv.x + nx0, x21 = xv.y + nx1;

    float2 wv = ((const float2*)Wa)[lane];
    float p = x20 * wv.x + x21 * wv.y;
#pragma unroll
    for (int o = 32; o > 0; o >>= 1) p += __shfl_xor(p, o);
    float a = 1.0f / (1.0f + expf(-(p + ba[0])));
    *(float2*)(out + (size_t)node * D + lane * 2) = make_float2(x20 * a, x21 * a);
}

// ---------------- fallback path (round-2 atomic pipeline) ----------------
__global__ __launch_bounds__(256) void scatter_kernel(
    const float* __restrict__ x, const int* __restrict__ esrc,
    const int* __restrict__ edst, float* __restrict__ agg,
    float* __restrict__ deg, int nE) {
    const int lane = threadIdx.x & 63;
    const int wave = (blockIdx.x * blockDim.x + threadIdx.x) >> 6;
    const int nw = (gridDim.x * blockDim.x) >> 6;
    const size_t feat = (size_t)(lane * 2);
    const float* xf = x + feat;
    float* af = agg + feat;
    for (int base = wave * 64; base < nE; base += nw * 64) {
        int e = base + lane;
        int s = 0, d = 0;
        if (e < nE) {
            s = esrc[e];
            d = edst[e];
            unsafeAtomicAdd(deg + d, 1.0f);
        }
        int cnt = nE - base; if (cnt > 64) cnt = 64;
        for (int i = 0; i < cnt; ++i) {
            int si = __builtin_amdgcn_readlane(s, i);
            int di = __builtin_amdgcn_readlane(d, i);
            float2 v = *(const float2*)(xf + (size_t)si * D);
            float* ap = af + (size_t)di * D;
            unsafeAtomicAdd(ap, v.x);
            unsafeAtomicAdd(ap + 1, v.y);
        }
    }
}

__global__ __launch_bounds__(256) void finalize_kernel(
    const float* x, const float* __restrict__ agg, const float* __restrict__ deg,
    const float* __restrict__ Wa, const float* __restrict__ ba,
    float* out, int nN) {
    const int lane = threadIdx.x & 63;
    const int wave = (blockIdx.x * blockDim.x + threadIdx.x) >> 6;
    const int nw = (gridDim.x * blockDim.x) >> 6;
    float2 wv = ((const float2*)Wa)[lane];
    float bias = ba[0];
    for (int n = wave; n < nN; n += nw) {
        float2 xv = ((const float2*)(x + (size_t)n * D))[lane];
        float2 av = ((const float2*)(agg + (size_t)n * D))[lane];
        float dg = deg[n];
        float inv = 1.0f / fmaxf(dg, 1.0f);
        float nx0 = (dg > 0.0f) ? av.x * inv : xv.x;
        float nx1 = (dg > 0.0f) ? av.y * inv : xv.y;
        float x20 = xv.x + nx0, x21 = xv.y + nx1;
        float p = x20 * wv.x + x21 * wv.y;
#pragma unroll
        for (int off = 32; off > 0; off >>= 1) p += __shfl_xor(p, off);
        float a = 1.0f / (1.0f + expf(-(p + bias)));
        *(float2*)(out + (size_t)n * D + lane * 2) = make_float2(x20 * a, x21 * a);
    }
}

extern "C" void kernel_launch(void* const* d_in, const int* in_sizes, int n_in,
                              void* d_out, int out_size, void* d_ws, size_t ws_size,
                              hipStream_t stream) {
    const float* nf     = (const float*)d_in[0];
    const int*   esrc   = (const int*)d_in[1];
    const int*   edst   = (const int*)d_in[2];
    const float* W_enc  = (const float*)d_in[3];
    const float* b_enc  = (const float*)d_in[4];
    const float* W_attn = (const float*)d_in[5];
    const float* b_attn = (const float*)d_in[6];
    float* out = (float*)d_out;
    const int nN = in_sizes[0] / D;
    const int nE = in_sizes[1];

    // CSR path ws layout: x[nN*D] | slots[nE] | offs[nN] | deg[nN] | cur[nN] |
    //                     gcur[64] | WT[D*D]   (~59 MB)
    const size_t need = ((size_t)nN * D + nE + 3 * (size_t)nN + 64 + D * D) * 4;

    if (ws_size >= need) {
        float* x     = (float*)d_ws;
        int*   slots = (int*)(x + (size_t)nN * D);
        int*   offs  = slots + nE;
        int*   deg   = offs + nN;
        int*   cur   = deg + nN;
        int*   gcur  = cur + nN;
        float* WT    = (float*)(gcur + 64);

        hipMemsetAsync(deg, 0, (2 * (size_t)nN + 64) * sizeof(int), stream);
        transpose_w_kernel<<<(D * D + 255) / 256, 256, 0, stream>>>(W_enc, WT);
        hist_kernel<<<(nE + 255) / 256, 256, 0, stream>>>(edst, deg, nE);
        offs_kernel<<<(nN + 255) / 256, 256, 0, stream>>>(deg, offs, gcur, nN);
        fill_kernel<<<(nE + 255) / 256, 256, 0, stream>>>(esrc, edst, offs, cur, slots, nE);
        encoder_kernel<<<(nN + 31) / 32, 256, 0, stream>>>(nf, WT, b_enc, x, nN);
        gather_finalize_kernel<<<(nN * 64 + 255) / 256, 256, 0, stream>>>(
            x, slots, offs, deg, W_attn, b_attn, out, nN);
    } else {
        // fallback: round-2 atomic pipeline (ws: agg | degf | WT)
        float* agg  = (float*)d_ws;
        float* degf = agg + (size_t)nN * D;
        float* WT   = degf + nN;
        hipMemsetAsync(d_ws, 0, ((size_t)nN * D + nN) * sizeof(float), stream);
        transpose_w_kernel<<<(D * D + 255) / 256, 256, 0, stream>>>(W_enc, WT);
        encoder_kernel<<<(nN + 31) / 32, 256, 0, stream>>>(nf, WT, b_enc, out, nN);
        scatter_kernel<<<2048, 256, 0, stream>>>(out, esrc, edst, agg, degf, nE);
        finalize_kernel<<<2048, 256, 0, stream>>>(out, agg, degf, W_attn, b_attn, out, nN);
    }
}

// Round 9
// 441.018 us; speedup vs baseline: 3.6403x; 1.0149x over previous
//
#include <hip/hip_runtime.h>
#include <math.h>

#define D 128

// ---------------- W transpose ----------------
__global__ void transpose_w_kernel(const float* __restrict__ W, float* __restrict__ WT) {
    int t = blockIdx.x * blockDim.x + threadIdx.x;
    if (t < D * D) {
        int c = t >> 7, k = t & (D - 1);
        WT[k * D + c] = W[c * D + k];
    }
}

__device__ __forceinline__ unsigned bf16_rne(float f) {
    unsigned u = __float_as_uint(f);
    return (u + 0x7FFFu + ((u >> 16) & 1u)) >> 16;
}

// ---------------- encoder ----------------
// x[n][c] = b[c] + sum_k nf[n][k] * W_enc[c][k]
// Writes fp32 x to out (residual path) AND bf16 copy xh to ws (gather path).
__global__ __launch_bounds__(256) void encoder_kernel(
    const float* __restrict__ nf, const float* __restrict__ WTg,
    const float* __restrict__ b, float* __restrict__ x,
    unsigned* __restrict__ xh, int nN) {
    __shared__ float WT[D * D];
    __shared__ float NF[32 * D];
    const int t = threadIdx.x;
    const int row0 = blockIdx.x * 32;

    for (int i = t; i < (D * D) / 4; i += 256)
        ((float4*)WT)[i] = ((const float4*)WTg)[i];
    for (int i = t; i < (32 * D) / 4; i += 256) {
        int r = i >> 5;
        int gr = row0 + r;
        float4 v = make_float4(0.f, 0.f, 0.f, 0.f);
        if (gr < nN) v = ((const float4*)(nf + (size_t)gr * D))[i & 31];
        ((float4*)NF)[i] = v;
    }
    __syncthreads();

    const int c4 = (t & 31) * 4;
    const int rg = t >> 5;
    float4 bv = *(const float4*)(b + c4);
    float acc[4][4];
#pragma unroll
    for (int r = 0; r < 4; ++r) {
        acc[r][0] = bv.x; acc[r][1] = bv.y; acc[r][2] = bv.z; acc[r][3] = bv.w;
    }
#pragma unroll 4
    for (int k = 0; k < D; k += 4) {
        float4 w0 = *(const float4*)(WT + (k + 0) * D + c4);
        float4 w1 = *(const float4*)(WT + (k + 1) * D + c4);
        float4 w2 = *(const float4*)(WT + (k + 2) * D + c4);
        float4 w3 = *(const float4*)(WT + (k + 3) * D + c4);
#pragma unroll
        for (int r = 0; r < 4; ++r) {
            float4 nv = *(const float4*)(NF + (rg * 4 + r) * D + k);
            acc[r][0] += nv.x * w0.x + nv.y * w1.x + nv.z * w2.x + nv.w * w3.x;
            acc[r][1] += nv.x * w0.y + nv.y * w1.y + nv.z * w2.y + nv.w * w3.y;
            acc[r][2] += nv.x * w0.z + nv.y * w1.z + nv.z * w2.z + nv.w * w3.z;
            acc[r][3] += nv.x * w0.w + nv.y * w1.w + nv.z * w2.w + nv.w * w3.w;
        }
    }
#pragma unroll
    for (int r = 0; r < 4; ++r) {
        int gr = row0 + rg * 4 + r;
        if (gr < nN) {
            *(float4*)(x + (size_t)gr * D + c4) =
                make_float4(acc[r][0], acc[r][1], acc[r][2], acc[r][3]);
            // bf16 pair-packed copy (features c4..c4+3 -> 2 uints)
            unsigned p0 = bf16_rne(acc[r][0]) | (bf16_rne(acc[r][1]) << 16);
            unsigned p1 = bf16_rne(acc[r][2]) | (bf16_rne(acc[r][3]) << 16);
            uint2* dst = (uint2*)(xh + (size_t)gr * (D / 2) + (c4 >> 1));
            *dst = make_uint2(p0, p1);
        }
    }
}

// ---------------- CSR build ----------------
// hist + phantom-init fused: slots pre-filled with nN (zero-row index).
__global__ void hist_init_kernel(const int* __restrict__ edst, int* __restrict__ deg,
                                 int* __restrict__ slots, int slotsCap,
                                 int nE, int nN) {
    int t = blockIdx.x * blockDim.x + threadIdx.x;
    if (t < slotsCap) slots[t] = nN;
    if (t < nE) atomicAdd(&deg[edst[t]], 1);
}

// offs/cur from PADDED degrees ((deg+7)&~7); range order arbitrary.
__global__ __launch_bounds__(256) void offs_kernel(
    const int* __restrict__ deg, int* __restrict__ offs, int* __restrict__ cur,
    int* __restrict__ gcur, int nN) {
    __shared__ int wsum[4];
    __shared__ int sbase;
    const int t = threadIdx.x, lane = t & 63, w = t >> 6;
    const int i = blockIdx.x * 256 + t;
    int d = (i < nN) ? deg[i] : 0;
    int pd = (d + 7) & ~7;
    int sc = pd;
#pragma unroll
    for (int o = 1; o < 64; o <<= 1) {
        int v = __shfl_up(sc, o);
        if (lane >= o) sc += v;
    }
    if (lane == 63) wsum[w] = sc;
    __syncthreads();
    if (t == 0) {
        int s0 = wsum[0], s1 = wsum[1], s2 = wsum[2], s3 = wsum[3];
        sbase = atomicAdd(gcur, s0 + s1 + s2 + s3);
        wsum[0] = 0; wsum[1] = s0; wsum[2] = s0 + s1; wsum[3] = s0 + s1 + s2;
    }
    __syncthreads();
    if (i < nN) {
        int base = sbase + wsum[w] + (sc - pd);
        offs[i] = base;
        cur[i] = base;
    }
}

__global__ void fill_kernel(const int* __restrict__ esrc, const int* __restrict__ edst,
                            int* __restrict__ cur, int* __restrict__ slots, int nE) {
    int e = blockIdx.x * blockDim.x + threadIdx.x;
    if (e < nE) {
        int pos = atomicAdd(&cur[edst[e]], 1);
        slots[pos] = esrc[e];
    }
}

// ---------------- fused gather + finalize ----------------
// One wave per dst node; lane owns features 2l,2l+1 (one uint = 2 bf16).
// Padded ranges -> inner loop always 8 gathers in flight, no serial tail.
// Phantom slots hit the L1-resident zero row (index nN).
__global__ __launch_bounds__(256) void gather_finalize_kernel(
    const unsigned* __restrict__ xh, const int* __restrict__ slots,
    const int* __restrict__ offs, const int* __restrict__ deg,
    const float* __restrict__ Wa, const float* __restrict__ ba,
    float* __restrict__ out, int nN) {
    const int lane = threadIdx.x & 63;
    const int node = (blockIdx.x * blockDim.x + threadIdx.x) >> 6;
    if (node >= nN) return;
    const int dg = deg[node];
    const int pdeg = (dg + 7) & ~7;
    const int off = offs[node];
    const unsigned* xr = xh + lane;   // +s*64 per row

    float2 a0 = make_float2(0.f, 0.f), a1 = a0, a2 = a0, a3 = a0;
    float2 a4 = a0, a5 = a0, a6 = a0, a7 = a0;
    for (int base = 0; base < pdeg; base += 64) {
        int cnt = pdeg - base; if (cnt > 64) cnt = 64;
        int sl = slots[off + base + lane];
        sl = (lane < cnt) ? sl : nN;
        for (int i = 0; i < cnt; i += 8) {
            int s0 = __builtin_amdgcn_readlane(sl, i);
            int s1 = __builtin_amdgcn_readlane(sl, i + 1);
            int s2 = __builtin_amdgcn_readlane(sl, i + 2);
            int s3 = __builtin_amdgcn_readlane(sl, i + 3);
            int s4 = __builtin_amdgcn_readlane(sl, i + 4);
            int s5 = __builtin_amdgcn_readlane(sl, i + 5);
            int s6 = __builtin_amdgcn_readlane(sl, i + 6);
            int s7 = __builtin_amdgcn_readlane(sl, i + 7);
            unsigned u0 = xr[(size_t)s0 * 64];
            unsigned u1 = xr[(size_t)s1 * 64];
            unsigned u2 = xr[(size_t)s2 * 64];
            unsigned u3 = xr[(size_t)s3 * 64];
            unsigned u4 = xr[(size_t)s4 * 64];
            unsigned u5 = xr[(size_t)s5 * 64];
            unsigned u6 = xr[(size_t)s6 * 64];
            unsigned u7 = xr[(size_t)s7 * 64];
            a0.x += __uint_as_float(u0 << 16); a0.y += __uint_as_float(u0 & 0xFFFF0000u);
            a1.x += __uint_as_float(u1 << 16); a1.y += __uint_as_float(u1 & 0xFFFF0000u);
            a2.x += __uint_as_float(u2 << 16); a2.y += __uint_as_float(u2 & 0xFFFF0000u);
            a3.x += __uint_as_float(u3 << 16); a3.y += __uint_as_float(u3 & 0xFFFF0000u);
            a4.x += __uint_as_float(u4 << 16); a4.y += __uint_as_float(u4 & 0xFFFF0000u);
            a5.x += __uint_as_float(u5 << 16); a5.y += __uint_as_float(u5 & 0xFFFF0000u);
            a6.x += __uint_as_float(u6 << 16); a6.y += __uint_as_float(u6 & 0xFFFF0000u);
            a7.x += __uint_as_float(u7 << 16); a7.y += __uint_as_float(u7 & 0xFFFF0000u);
        }
    }
    float sx = ((a0.x + a1.x) + (a2.x + a3.x)) + ((a4.x + a5.x) + (a6.x + a7.x));
    float sy = ((a0.y + a1.y) + (a2.y + a3.y)) + ((a4.y + a5.y) + (a6.y + a7.y));

    // own row fp32 from out (exclusive per-wave row: safe read-modify-write)
    float2 xv = ((const float2*)(out + (size_t)node * D))[lane];
    float inv = (dg > 0) ? 1.0f / (float)dg : 0.f;
    float nx0 = (dg > 0) ? sx * inv : xv.x;
    float nx1 = (dg > 0) ? sy * inv : xv.y;
    float x20 = xv.x + nx0, x21 = xv.y + nx1;

    float2 wv = ((const float2*)Wa)[lane];
    float p = x20 * wv.x + x21 * wv.y;
#pragma unroll
    for (int o = 32; o > 0; o >>= 1) p += __shfl_xor(p, o);
    float a = 1.0f / (1.0f + expf(-(p + ba[0])));
    ((float2*)(out + (size_t)node * D))[lane] = make_float2(x20 * a, x21 * a);
}

// ---------------- fallback (atomic pipeline, proven-correct) ----------------
__global__ __launch_bounds__(256) void scatter_kernel(
    const float* __restrict__ x, const int* __restrict__ esrc,
    const int* __restrict__ edst, float* __restrict__ agg,
    float* __restrict__ deg, int nE) {
    const int lane = threadIdx.x & 63;
    const int wave = (blockIdx.x * blockDim.x + threadIdx.x) >> 6;
    const int nw = (gridDim.x * blockDim.x) >> 6;
    const size_t feat = (size_t)(lane * 2);
    const float* xf = x + feat;
    float* af = agg + feat;
    for (int base = wave * 64; base < nE; base += nw * 64) {
        int e = base + lane;
        int s = 0, d = 0;
        if (e < nE) {
            s = esrc[e];
            d = edst[e];
            unsafeAtomicAdd(deg + d, 1.0f);
        }
        int cnt = nE - base; if (cnt > 64) cnt = 64;
        for (int i = 0; i < cnt; ++i) {
            int si = __builtin_amdgcn_readlane(s, i);
            int di = __builtin_amdgcn_readlane(d, i);
            float2 v = *(const float2*)(xf + (size_t)si * D);
            float* ap = af + (size_t)di * D;
            unsafeAtomicAdd(ap, v.x);
            unsafeAtomicAdd(ap + 1, v.y);
        }
    }
}

__global__ __launch_bounds__(256) void finalize_kernel(
    const float* x, const float* __restrict__ agg, const float* __restrict__ deg,
    const float* __restrict__ Wa, const float* __restrict__ ba,
    float* out, int nN) {
    const int lane = threadIdx.x & 63;
    const int wave = (blockIdx.x * blockDim.x + threadIdx.x) >> 6;
    const int nw = (gridDim.x * blockDim.x) >> 6;
    float2 wv = ((const float2*)Wa)[lane];
    float bias = ba[0];
    for (int n = wave; n < nN; n += nw) {
        float2 xv = ((const float2*)(x + (size_t)n * D))[lane];
        float2 av = ((const float2*)(agg + (size_t)n * D))[lane];
        float dg = deg[n];
        float inv = 1.0f / fmaxf(dg, 1.0f);
        float nx0 = (dg > 0.0f) ? av.x * inv : xv.x;
        float nx1 = (dg > 0.0f) ? av.y * inv : xv.y;
        float x20 = xv.x + nx0, x21 = xv.y + nx1;
        float p = x20 * wv.x + x21 * wv.y;
#pragma unroll
        for (int off = 32; off > 0; off >>= 1) p += __shfl_xor(p, off);
        float a = 1.0f / (1.0f + expf(-(p + bias)));
        *(float2*)(out + (size_t)n * D + lane * 2) = make_float2(x20 * a, x21 * a);
    }
}

extern "C" void kernel_launch(void* const* d_in, const int* in_sizes, int n_in,
                              void* d_out, int out_size, void* d_ws, size_t ws_size,
                              hipStream_t stream) {
    const float* nf     = (const float*)d_in[0];
    const int*   esrc   = (const int*)d_in[1];
    const int*   edst   = (const int*)d_in[2];
    const float* W_enc  = (const float*)d_in[3];
    const float* b_enc  = (const float*)d_in[4];
    const float* W_attn = (const float*)d_in[5];
    const float* b_attn = (const float*)d_in[6];
    float* out = (float*)d_out;
    const int nN = in_sizes[0] / D;
    const int nE = in_sizes[1];

    // ws layout: xh[(nN+1)*D bf16] | slots[slotsCap] | offs[nN] | deg[nN] |
    //            gcur[64] | cur[nN] | WT[D*D]   (~36 MB, under proven bound)
    const int slotsCap = nE + 7 * nN + 64;
    const size_t xhWords = ((size_t)(nN + 1) * D) / 2;   // uints
    const size_t need = (xhWords + (size_t)slotsCap + 3 * (size_t)nN + 64 + D * D) * 4;

    if (ws_size >= need) {
        unsigned* xh   = (unsigned*)d_ws;
        int*      slots = (int*)(xh + xhWords);
        int*      offs  = slots + slotsCap;
        int*      deg   = offs + nN;
        int*      gcur  = deg + nN;
        int*      cur   = gcur + 64;
        float*    WT    = (float*)(cur + nN);

        hipMemsetAsync(deg, 0, ((size_t)nN + 64) * sizeof(int), stream);          // deg+gcur
        hipMemsetAsync(xh + (size_t)nN * (D / 2), 0, D * 2, stream);              // zero row
        transpose_w_kernel<<<(D * D + 255) / 256, 256, 0, stream>>>(W_enc, WT);
        hist_init_kernel<<<(slotsCap + 255) / 256, 256, 0, stream>>>(
            edst, deg, slots, slotsCap, nE, nN);
        offs_kernel<<<(nN + 255) / 256, 256, 0, stream>>>(deg, offs, cur, gcur, nN);
        fill_kernel<<<(nE + 255) / 256, 256, 0, stream>>>(esrc, edst, cur, slots, nE);
        encoder_kernel<<<(nN + 31) / 32, 256, 0, stream>>>(nf, WT, b_enc, out, xh, nN);
        gather_finalize_kernel<<<(nN * 64 + 255) / 256, 256, 0, stream>>>(
            xh, slots, offs, deg, W_attn, b_attn, out, nN);
    } else {
        // fallback: atomic pipeline (ws: agg | degf | WT)
        float* agg  = (float*)d_ws;
        float* degf = agg + (size_t)nN * D;
        float* WT   = degf + nN;
        hipMemsetAsync(d_ws, 0, ((size_t)nN * D + nN) * sizeof(float), stream);
        transpose_w_kernel<<<(D * D + 255) / 256, 256, 0, stream>>>(W_enc, WT);
        encoder_kernel<<<(nN + 31) / 32, 256, 0, stream>>>(nf, WT, b_enc, out,
                                                           (unsigned*)WT, 0);
        scatter_kernel<<<2048, 256, 0, stream>>>(out, esrc, edst, agg, degf, nE);
        finalize_kernel<<<2048, 256, 0, stream>>>(out, agg, degf, W_attn, b_attn, out, nN);
    }
}